// Round 20
// baseline (115.028 us; speedup 1.0000x reference)
//
#include <hip/hip_runtime.h>

typedef __bf16 bf16_t;
typedef float  f32x4  __attribute__((ext_vector_type(4)));
typedef int    i32x4  __attribute__((ext_vector_type(4)));
typedef int    i32x8  __attribute__((ext_vector_type(8)));
typedef unsigned char u8;
typedef unsigned long long u64;

#define B_DIM 4
#define S_DIM 4096
#define D_DIM 1024
#define M_DIM (B_DIM * S_DIM)   // 16384 rows

#define CHUNK 32   // scan output steps per block
#define WARM  16   // scan warm-up steps

__device__ __forceinline__ void g2l16(const void* g, void* l) {
  __builtin_amdgcn_global_load_lds(
      (const __attribute__((address_space(1))) void*)g,
      (__attribute__((address_space(3))) void*)l, 16, 0, 0);
}

// ------- LayerNorm fp32 -> fp8 e4m3 (linear); 4 rows/block, wave/row ------
__global__ __launch_bounds__(256) void ln_kernel(
    const float* __restrict__ x, const float* __restrict__ gamma,
    const float* __restrict__ beta, u8* __restrict__ h) {
  const int row  = blockIdx.x * 4 + (threadIdx.x >> 6);
  const int lane = threadIdx.x & 63;
  const float4* xr = (const float4*)(x + (size_t)row * D_DIM);
  float4 v[4];
  float s = 0.f, s2 = 0.f;
#pragma unroll
  for (int j = 0; j < 4; ++j) {
    v[j] = xr[j * 64 + lane];
    s += v[j].x + v[j].y + v[j].z + v[j].w;
    s2 = fmaf(v[j].x, v[j].x, s2);
    s2 = fmaf(v[j].y, v[j].y, s2);
    s2 = fmaf(v[j].z, v[j].z, s2);
    s2 = fmaf(v[j].w, v[j].w, s2);
  }
#pragma unroll
  for (int off = 32; off; off >>= 1) {
    s  += __shfl_xor(s, off);
    s2 += __shfl_xor(s2, off);
  }
  const float mu  = s * (1.f / (float)D_DIM);
  const float var = fmaf(-mu, mu, s2 * (1.f / (float)D_DIM));
  const float inv = rsqrtf(var + 1e-5f);
  int* hr = (int*)(h + (size_t)row * D_DIM);
#pragma unroll
  for (int j = 0; j < 4; ++j) {
    const float4 g4 = ((const float4*)gamma)[j * 64 + lane];
    const float4 b4 = ((const float4*)beta)[j * 64 + lane];
    const float o0 = fmaf((v[j].x - mu) * inv, g4.x, b4.x);
    const float o1 = fmaf((v[j].y - mu) * inv, g4.y, b4.y);
    const float o2 = fmaf((v[j].z - mu) * inv, g4.z, b4.z);
    const float o3 = fmaf((v[j].w - mu) * inv, g4.w, b4.w);
    int p = __builtin_amdgcn_cvt_pk_fp8_f32(o0, o1, 0, false);
    p = __builtin_amdgcn_cvt_pk_fp8_f32(o2, o3, p, true);
    hr[j * 64 + lane] = p;
  }
}

// -- both W [K][N] fp32 -> WT [N][K] fp8 e4m3 (linear), x16; z picks W -----
__global__ __launch_bounds__(256) void transpose_fp8_kernel(
    const float* __restrict__ W0, u8* __restrict__ WT0,
    const float* __restrict__ W1, u8* __restrict__ WT1) {
  const float* W  = blockIdx.z ? W1 : W0;
  u8*          WT = blockIdx.z ? WT1 : WT0;
  __shared__ float tile[32][33];
  const int tx = threadIdx.x & 31;
  const int ty = threadIdx.x >> 5;
  const int bn = blockIdx.x * 32;
  const int bk = blockIdx.y * 32;
#pragma unroll
  for (int i = 0; i < 32; i += 8)
    tile[ty + i][tx] = W[(size_t)(bk + ty + i) * D_DIM + bn + tx];
  __syncthreads();
#pragma unroll
  for (int i = 0; i < 32; i += 8) {
    const int p =
        __builtin_amdgcn_cvt_pk_fp8_f32(16.f * tile[tx][ty + i], 0.f, 0, false);
    WT[(size_t)(bn + ty + i) * D_DIM + bk + tx] = (u8)(p & 0xff);
  }
}

// ====== MX-fp8 NT GEMM: 128x256 tile, 8 waves, BK=128, K=128 MFMA =========
// MODE 0 (GEMM1): h8 x (16*W_in)  -> c8 = fp8(acc/16 + bias)
// MODE 1 (GEMM2): (16*y8) x (16*W_out) -> f32 out = xres + acc/256 + bias
// Staged bytes 201MB (-25% vs 128^2); 8 waves (2M x 4N), wave 64x64 out,
// ~128 regs/wave (R17 budget, no spill). LDS buf (48KB): A [128r][128B] @0
// | B [256r][128B] @16384; unit u of a row at phys u ^ (row&7) [verified].
#define NMX 8   // K / 128

__device__ __forceinline__ i32x8 ldfrag(const char* region, int row, int g) {
  const int x = row & 7;
  const i32x4 lo =
      *(const i32x4*)(region + row * 128 + ((((g << 1)) ^ x) << 4));
  const i32x4 hi =
      *(const i32x4*)(region + row * 128 + ((((g << 1) | 1) ^ x) << 4));
  i32x8 r;
  r[0] = lo[0]; r[1] = lo[1]; r[2] = lo[2]; r[3] = lo[3];
  r[4] = hi[0]; r[5] = hi[1]; r[6] = hi[2]; r[7] = hi[3];
  return r;
}

template <int MODE>
__global__ __launch_bounds__(512, 2) void gemm_mx_kernel(
    const u8* __restrict__ A, const u8* __restrict__ BT,
    const float* __restrict__ bias, const float* __restrict__ xres,
    void* __restrict__ Cout) {
  __shared__ __attribute__((aligned(16))) char lds[2][49152];
  const int tid  = threadIdx.x;
  const int lane = tid & 63;
  const int wave = tid >> 6;          // 0..7
  const int wr = wave >> 2;           // 0..1 (M half: 64 rows)
  const int wc = wave & 3;            // 0..3 (N quarter: 64 cols)
  const int bid = blockIdx.x;
  const int swz = (bid & 7) * 64 + (bid >> 3);   // 512 blocks, 8 XCDs
  const int m0 = (swz >> 2) * 128;    // 128 m-panels
  const int n0 = (swz & 3) * 256;     // 4 n-panels

  // staging: dest unit i = tid + j*512 -> (row = i>>3, phys p = i&7);
  // row = (tid>>3) + j*64 so row&7 = (tid>>3)&7 invariant across j.
  const int srow = tid >> 3;          // 0..63
  const int us   = (((tid & 7) ^ (srow & 7)) << 4);
  const u8* srcA = A  + (size_t)(m0 + srow) * D_DIM + us;
  const u8* srcB = BT + (size_t)(n0 + srow) * D_DIM + us;
  const int dst0 = tid * 16;

  const int frow = lane & 15;
  const int g    = lane >> 4;

  f32x4 acc[4][4];
#pragma unroll
  for (int m = 0; m < 4; ++m)
#pragma unroll
    for (int n = 0; n < 4; ++n) acc[m][n] = (f32x4){0.f, 0.f, 0.f, 0.f};

#define STAGE(T)                                                 \
  {                                                              \
    char* dst = lds[(T) & 1];                                    \
    const size_t ko = (size_t)(T) * 128;                         \
    g2l16(srcA + ko,                       dst + dst0);          \
    g2l16(srcA + (size_t)64  * D_DIM + ko, dst + 8192 + dst0);   \
    g2l16(srcB + ko,                       dst + 16384 + dst0);  \
    g2l16(srcB + (size_t)64  * D_DIM + ko, dst + 24576 + dst0);  \
    g2l16(srcB + (size_t)128 * D_DIM + ko, dst + 32768 + dst0);  \
    g2l16(srcB + (size_t)192 * D_DIM + ko, dst + 40960 + dst0);  \
  }

  STAGE(0);
  for (int t = 0; t < NMX; ++t) {
    __syncthreads();   // stage(t) DMA drained; prev readers of buf done
    const char* buf = lds[t & 1];
    i32x8 af[4], bf[4];
#pragma unroll
    for (int m = 0; m < 4; ++m)
      af[m] = ldfrag(buf, wr * 64 + m * 16 + frow, g);
#pragma unroll
    for (int n = 0; n < 4; ++n)
      bf[n] = ldfrag(buf + 16384, wc * 64 + n * 16 + frow, g);
    if (t + 1 < NMX) STAGE(t + 1);
#pragma unroll
    for (int m = 0; m < 4; ++m)
#pragma unroll
      for (int n = 0; n < 4; ++n)
        acc[m][n] = __builtin_amdgcn_mfma_scale_f32_16x16x128_f8f6f4(
            af[m], bf[n], acc[m][n], 0, 0,
            0, 0x7f7f7f7f, 0, 0x7f7f7f7f);   // E8M0 127 = 1.0 (all bytes)
  }
#undef STAGE

  // epilogue: C/D layout col = lane&15, row = (lane>>4)*4 + r
  const int rbase = m0 + wr * 64 + ((lane >> 4) << 2);
  const int cbase = n0 + wc * 64 + (lane & 15);
#pragma unroll
  for (int n = 0; n < 4; ++n) {
    const int col = cbase + n * 16;
    const float bn = bias[col];
#pragma unroll
    for (int m = 0; m < 4; ++m) {
      const int row = rbase + m * 16;
#pragma unroll
      for (int r = 0; r < 4; ++r) {
        const size_t idx = (size_t)(row + r) * D_DIM + col;
        if (MODE == 0) {
          const float cv = fmaf(acc[m][n][r], 0.0625f, bn);
          const int p = __builtin_amdgcn_cvt_pk_fp8_f32(cv, 0.f, 0, false);
          ((u8*)Cout)[idx] = (u8)(p & 0xff);
        } else {
          ((float*)Cout)[idx] =
              xres[idx] + fmaf(acc[m][n][r], 1.f / 256.f, bn);
        }
      }
    }
  }
}

// --- chunked chaotic scan: c fp8 linear in, y fp8 x16 linear out ----------
__global__ __launch_bounds__(64) void scan_kernel(
    const u8* __restrict__ c, u8* __restrict__ y) {
  const int b     = blockIdx.y;
  const int chunk = blockIdx.x;
  const int t0    = chunk * CHUNK;
  const int start = (chunk == 0) ? 0 : t0 - WARM;
  const int tend  = t0 + CHUNK;
  const int lane  = threadIdx.x;

  float zre[8], zim[8];
#pragma unroll
  for (int j = 0; j < 8; ++j) { zre[j] = 0.f; zim[j] = 0.f; }

  const u8* crow = c + ((size_t)b * S_DIM + start) * D_DIM;
  u64 cr = *(const u64*)(crow + lane * 8);
  u64 ci = *(const u64*)(crow + 512 + lane * 8);

  for (int t = start; t < tend; ++t) {
    u64 crn = cr, cin = ci;
    if (t + 1 < tend) {
      const u8* nrow = c + ((size_t)b * S_DIM + (t + 1)) * D_DIM;
      crn = *(const u64*)(nrow + lane * 8);
      cin = *(const u64*)(nrow + 512 + lane * 8);
    }
    float cre[8], cim[8];
    {
      const unsigned rl = (unsigned)cr, rh = (unsigned)(cr >> 32);
      const unsigned il = (unsigned)ci, ih = (unsigned)(ci >> 32);
      cre[0] = __builtin_amdgcn_cvt_f32_fp8(rl, 0);
      cre[1] = __builtin_amdgcn_cvt_f32_fp8(rl, 1);
      cre[2] = __builtin_amdgcn_cvt_f32_fp8(rl, 2);
      cre[3] = __builtin_amdgcn_cvt_f32_fp8(rl, 3);
      cre[4] = __builtin_amdgcn_cvt_f32_fp8(rh, 0);
      cre[5] = __builtin_amdgcn_cvt_f32_fp8(rh, 1);
      cre[6] = __builtin_amdgcn_cvt_f32_fp8(rh, 2);
      cre[7] = __builtin_amdgcn_cvt_f32_fp8(rh, 3);
      cim[0] = __builtin_amdgcn_cvt_f32_fp8(il, 0);
      cim[1] = __builtin_amdgcn_cvt_f32_fp8(il, 1);
      cim[2] = __builtin_amdgcn_cvt_f32_fp8(il, 2);
      cim[3] = __builtin_amdgcn_cvt_f32_fp8(il, 3);
      cim[4] = __builtin_amdgcn_cvt_f32_fp8(ih, 0);
      cim[5] = __builtin_amdgcn_cvt_f32_fp8(ih, 1);
      cim[6] = __builtin_amdgcn_cvt_f32_fp8(ih, 2);
      cim[7] = __builtin_amdgcn_cvt_f32_fp8(ih, 3);
    }
    float nr[8], ni[8];
    float ss = 0.f;
#pragma unroll
    for (int j = 0; j < 8; ++j) {
      const float a  = zre[j], bb = zim[j];
      const float rr = fmaf(a, a, fmaf(-bb, bb, cre[j]));
      const float ii = fmaf(2.f * a, bb, cim[j]);
      nr[j] = rr; ni[j] = ii;
      ss = fmaf(rr, rr, ss);
      ss = fmaf(ii, ii, ss);
    }
#pragma unroll
    for (int off = 32; off; off >>= 1) ss += __shfl_xor(ss, off);
    const float nrm = sqrtf(ss + 1e-12f);
    const float sc  = 2.0f / fmaxf(nrm, 2.0f);
#pragma unroll
    for (int j = 0; j < 8; ++j) { zre[j] = nr[j] * sc; zim[j] = ni[j] * sc; }
    if (t >= t0) {
      u8* yrow = y + ((size_t)b * S_DIM + t) * D_DIM;
      int pr0 = __builtin_amdgcn_cvt_pk_fp8_f32(16.f * zre[0], 16.f * zre[1], 0, false);
      pr0 = __builtin_amdgcn_cvt_pk_fp8_f32(16.f * zre[2], 16.f * zre[3], pr0, true);
      int pr1 = __builtin_amdgcn_cvt_pk_fp8_f32(16.f * zre[4], 16.f * zre[5], 0, false);
      pr1 = __builtin_amdgcn_cvt_pk_fp8_f32(16.f * zre[6], 16.f * zre[7], pr1, true);
      int pi0 = __builtin_amdgcn_cvt_pk_fp8_f32(16.f * zim[0], 16.f * zim[1], 0, false);
      pi0 = __builtin_amdgcn_cvt_pk_fp8_f32(16.f * zim[2], 16.f * zim[3], pi0, true);
      int pi1 = __builtin_amdgcn_cvt_pk_fp8_f32(16.f * zim[4], 16.f * zim[5], 0, false);
      pi1 = __builtin_amdgcn_cvt_pk_fp8_f32(16.f * zim[6], 16.f * zim[7], pi1, true);
      *(u64*)(yrow + lane * 8)       = ((u64)(unsigned)pr1 << 32) | (unsigned)pr0;
      *(u64*)(yrow + 512 + lane * 8) = ((u64)(unsigned)pi1 << 32) | (unsigned)pi0;
    }
    cr = crn; ci = cin;
  }
}

extern "C" void kernel_launch(void* const* d_in, const int* in_sizes, int n_in,
                              void* d_out, int out_size, void* d_ws, size_t ws_size,
                              hipStream_t stream) {
  const float* x     = (const float*)d_in[0];
  const float* gamma = (const float*)d_in[1];
  const float* beta  = (const float*)d_in[2];
  const float* W_in  = (const float*)d_in[3];
  const float* b_in  = (const float*)d_in[4];
  const float* W_out = (const float*)d_in[5];
  const float* b_out = (const float*)d_in[6];
  float* out = (float*)d_out;

  char* ws = (char*)d_ws;
  u8* hy8  = (u8*)(ws);                  // 16 MiB: h fp8, then y fp8 (alias)
  u8* c8   = (u8*)(ws + (16ull << 20));  // 16 MiB: c fp8
  u8* wti8 = (u8*)(ws + (64ull << 20));  // 1 MiB:  W_in^T  fp8 (x16)
  u8* wto8 = (u8*)(ws + (65ull << 20));  // 1 MiB:  W_out^T fp8 (x16)

  transpose_fp8_kernel<<<dim3(32, 32, 2), 256, 0, stream>>>(W_in, wti8,
                                                            W_out, wto8);
  ln_kernel<<<M_DIM / 4, 256, 0, stream>>>(x, gamma, beta, hy8);
  gemm_mx_kernel<0><<<512, 512, 0, stream>>>(hy8, wti8, b_in, nullptr, c8);
  scan_kernel<<<dim3(S_DIM / CHUNK, B_DIM), 64, 0, stream>>>(c8, hy8);
  gemm_mx_kernel<1><<<512, 512, 0, stream>>>(hy8, wto8, b_out, x, out);
}

// Round 21
// 109.225 us; speedup vs baseline: 1.0531x; 1.0531x over previous
//
#include <hip/hip_runtime.h>

typedef __bf16 bf16_t;
typedef float  f32x4  __attribute__((ext_vector_type(4)));
typedef int    i32x4  __attribute__((ext_vector_type(4)));
typedef int    i32x8  __attribute__((ext_vector_type(8)));
typedef unsigned char u8;
typedef unsigned long long u64;

#define B_DIM 4
#define S_DIM 4096
#define D_DIM 1024
#define M_DIM (B_DIM * S_DIM)   // 16384 rows

#define CHUNK 32   // scan output steps per block
#define WARM  16   // scan warm-up steps

__device__ __forceinline__ void g2l16(const void* g, void* l) {
  __builtin_amdgcn_global_load_lds(
      (const __attribute__((address_space(1))) void*)g,
      (__attribute__((address_space(3))) void*)l, 16, 0, 0);
}

// ------- LayerNorm fp32 -> fp8 e4m3 (linear); 4 rows/block, wave/row ------
__global__ __launch_bounds__(256) void ln_kernel(
    const float* __restrict__ x, const float* __restrict__ gamma,
    const float* __restrict__ beta, u8* __restrict__ h) {
  const int row  = blockIdx.x * 4 + (threadIdx.x >> 6);
  const int lane = threadIdx.x & 63;
  const float4* xr = (const float4*)(x + (size_t)row * D_DIM);
  float4 v[4];
  float s = 0.f, s2 = 0.f;
#pragma unroll
  for (int j = 0; j < 4; ++j) {
    v[j] = xr[j * 64 + lane];
    s += v[j].x + v[j].y + v[j].z + v[j].w;
    s2 = fmaf(v[j].x, v[j].x, s2);
    s2 = fmaf(v[j].y, v[j].y, s2);
    s2 = fmaf(v[j].z, v[j].z, s2);
    s2 = fmaf(v[j].w, v[j].w, s2);
  }
#pragma unroll
  for (int off = 32; off; off >>= 1) {
    s  += __shfl_xor(s, off);
    s2 += __shfl_xor(s2, off);
  }
  const float mu  = s * (1.f / (float)D_DIM);
  const float var = fmaf(-mu, mu, s2 * (1.f / (float)D_DIM));
  const float inv = rsqrtf(var + 1e-5f);
  int* hr = (int*)(h + (size_t)row * D_DIM);
#pragma unroll
  for (int j = 0; j < 4; ++j) {
    const float4 g4 = ((const float4*)gamma)[j * 64 + lane];
    const float4 b4 = ((const float4*)beta)[j * 64 + lane];
    const float o0 = fmaf((v[j].x - mu) * inv, g4.x, b4.x);
    const float o1 = fmaf((v[j].y - mu) * inv, g4.y, b4.y);
    const float o2 = fmaf((v[j].z - mu) * inv, g4.z, b4.z);
    const float o3 = fmaf((v[j].w - mu) * inv, g4.w, b4.w);
    int p = __builtin_amdgcn_cvt_pk_fp8_f32(o0, o1, 0, false);
    p = __builtin_amdgcn_cvt_pk_fp8_f32(o2, o3, p, true);
    hr[j * 64 + lane] = p;
  }
}

// -- both W [K][N] fp32 -> WT [N][K] fp8 e4m3 (linear), x16; z picks W -----
__global__ __launch_bounds__(256) void transpose_fp8_kernel(
    const float* __restrict__ W0, u8* __restrict__ WT0,
    const float* __restrict__ W1, u8* __restrict__ WT1) {
  const float* W  = blockIdx.z ? W1 : W0;
  u8*          WT = blockIdx.z ? WT1 : WT0;
  __shared__ float tile[32][33];
  const int tx = threadIdx.x & 31;
  const int ty = threadIdx.x >> 5;
  const int bn = blockIdx.x * 32;
  const int bk = blockIdx.y * 32;
#pragma unroll
  for (int i = 0; i < 32; i += 8)
    tile[ty + i][tx] = W[(size_t)(bk + ty + i) * D_DIM + bn + tx];
  __syncthreads();
#pragma unroll
  for (int i = 0; i < 32; i += 8) {
    const int p =
        __builtin_amdgcn_cvt_pk_fp8_f32(16.f * tile[tx][ty + i], 0.f, 0, false);
    WT[(size_t)(bn + ty + i) * D_DIM + bk + tx] = (u8)(p & 0xff);
  }
}

// ====== MX-fp8 NT GEMM: 128x128 tile, 4 waves, BK=128, K=128 MFMA =========
// MODE 0 (GEMM1): h8 x (16*W_in)  -> c8 = fp8(acc/16 + bias)
// MODE 1 (GEMM2): (16*y8) x (16*W_out) -> f32 out = xres + acc/256 + bias
// [R15/R17 config verbatim — session best: ~35 us/GEMM, no spill, 0 confl]
#define NMX 8   // K / 128

__device__ __forceinline__ i32x8 ldfrag(const char* region, int row, int g) {
  const int x = row & 7;
  const i32x4 lo =
      *(const i32x4*)(region + row * 128 + ((((g << 1)) ^ x) << 4));
  const i32x4 hi =
      *(const i32x4*)(region + row * 128 + ((((g << 1) | 1) ^ x) << 4));
  i32x8 r;
  r[0] = lo[0]; r[1] = lo[1]; r[2] = lo[2]; r[3] = lo[3];
  r[4] = hi[0]; r[5] = hi[1]; r[6] = hi[2]; r[7] = hi[3];
  return r;
}

template <int MODE>
__global__ __launch_bounds__(256, 2) void gemm_mx_kernel(
    const u8* __restrict__ A, const u8* __restrict__ BT,
    const float* __restrict__ bias, const float* __restrict__ xres,
    void* __restrict__ Cout) {
  __shared__ __attribute__((aligned(16))) char lds[2][32768];
  const int tid  = threadIdx.x;
  const int lane = tid & 63;
  const int wave = tid >> 6;          // 0..3
  const int wr = wave >> 1;           // 0..1 (M half: 64 rows)
  const int wc = wave & 1;            // 0..1 (N half: 64 cols)
  const int bid = blockIdx.x;
  const int swz = (bid & 7) * 128 + (bid >> 3);  // 1024 blocks, 8 XCDs
  const int m0 = (swz >> 3) * 128;    // 128 m-panels
  const int n0 = (swz & 7) * 128;     // 8 n-panels

  const int srow = tid >> 3;          // 0..31
  const int us   = (((tid & 7) ^ (srow & 7)) << 4);
  const u8* srcA = A  + (size_t)(m0 + srow) * D_DIM + us;
  const u8* srcB = BT + (size_t)(n0 + srow) * D_DIM + us;
  const int dst0 = tid * 16;

  const int frow = lane & 15;
  const int g    = lane >> 4;

  f32x4 acc[4][4];
#pragma unroll
  for (int m = 0; m < 4; ++m)
#pragma unroll
    for (int n = 0; n < 4; ++n) acc[m][n] = (f32x4){0.f, 0.f, 0.f, 0.f};

#define STAGE(T)                                             \
  {                                                          \
    char* dst = lds[(T) & 1];                                \
    const size_t ko = (size_t)(T) * 128;                     \
    g2l16(srcA + ko,                          dst + dst0);   \
    g2l16(srcA + (size_t)32 * D_DIM + ko, dst + 4096 + dst0);  \
    g2l16(srcA + (size_t)64 * D_DIM + ko, dst + 8192 + dst0);  \
    g2l16(srcA + (size_t)96 * D_DIM + ko, dst + 12288 + dst0); \
    g2l16(srcB + ko,                      dst + 16384 + dst0); \
    g2l16(srcB + (size_t)32 * D_DIM + ko, dst + 20480 + dst0); \
    g2l16(srcB + (size_t)64 * D_DIM + ko, dst + 24576 + dst0); \
    g2l16(srcB + (size_t)96 * D_DIM + ko, dst + 28672 + dst0); \
  }

  STAGE(0);
  for (int t = 0; t < NMX; ++t) {
    __syncthreads();   // stage(t) DMA drained; prev readers of buf done
    const char* buf = lds[t & 1];
    i32x8 af[4], bf[4];
#pragma unroll
    for (int m = 0; m < 4; ++m)
      af[m] = ldfrag(buf, wr * 64 + m * 16 + frow, g);
#pragma unroll
    for (int n = 0; n < 4; ++n)
      bf[n] = ldfrag(buf + 16384, wc * 64 + n * 16 + frow, g);
    if (t + 1 < NMX) STAGE(t + 1);
#pragma unroll
    for (int m = 0; m < 4; ++m)
#pragma unroll
      for (int n = 0; n < 4; ++n)
        acc[m][n] = __builtin_amdgcn_mfma_scale_f32_16x16x128_f8f6f4(
            af[m], bf[n], acc[m][n], 0, 0,
            0, 0x7f7f7f7f, 0, 0x7f7f7f7f);   // E8M0 127 = 1.0 (all bytes)
  }
#undef STAGE

  // epilogue: C/D layout col = lane&15, row = (lane>>4)*4 + r
  const int rbase = m0 + wr * 64 + ((lane >> 4) << 2);
  const int cbase = n0 + wc * 64 + (lane & 15);
#pragma unroll
  for (int n = 0; n < 4; ++n) {
    const int col = cbase + n * 16;
    const float bn = bias[col];
#pragma unroll
    for (int m = 0; m < 4; ++m) {
      const int row = rbase + m * 16;
#pragma unroll
      for (int r = 0; r < 4; ++r) {
        const size_t idx = (size_t)(row + r) * D_DIM + col;
        if (MODE == 0) {
          const float cv = fmaf(acc[m][n][r], 0.0625f, bn);
          const int p = __builtin_amdgcn_cvt_pk_fp8_f32(cv, 0.f, 0, false);
          ((u8*)Cout)[idx] = (u8)(p & 0xff);
        } else {
          ((float*)Cout)[idx] =
              xres[idx] + fmaf(acc[m][n][r], 1.f / 256.f, bn);
        }
      }
    }
  }
}

// --- chunked chaotic scan: c fp8 linear in, y fp8 x16 linear out ----------
__global__ __launch_bounds__(64) void scan_kernel(
    const u8* __restrict__ c, u8* __restrict__ y) {
  const int b     = blockIdx.y;
  const int chunk = blockIdx.x;
  const int t0    = chunk * CHUNK;
  const int start = (chunk == 0) ? 0 : t0 - WARM;
  const int tend  = t0 + CHUNK;
  const int lane  = threadIdx.x;

  float zre[8], zim[8];
#pragma unroll
  for (int j = 0; j < 8; ++j) { zre[j] = 0.f; zim[j] = 0.f; }

  const u8* crow = c + ((size_t)b * S_DIM + start) * D_DIM;
  u64 cr = *(const u64*)(crow + lane * 8);
  u64 ci = *(const u64*)(crow + 512 + lane * 8);

  for (int t = start; t < tend; ++t) {
    u64 crn = cr, cin = ci;
    if (t + 1 < tend) {
      const u8* nrow = c + ((size_t)b * S_DIM + (t + 1)) * D_DIM;
      crn = *(const u64*)(nrow + lane * 8);
      cin = *(const u64*)(nrow + 512 + lane * 8);
    }
    float cre[8], cim[8];
    {
      const unsigned rl = (unsigned)cr, rh = (unsigned)(cr >> 32);
      const unsigned il = (unsigned)ci, ih = (unsigned)(ci >> 32);
      cre[0] = __builtin_amdgcn_cvt_f32_fp8(rl, 0);
      cre[1] = __builtin_amdgcn_cvt_f32_fp8(rl, 1);
      cre[2] = __builtin_amdgcn_cvt_f32_fp8(rl, 2);
      cre[3] = __builtin_amdgcn_cvt_f32_fp8(rl, 3);
      cre[4] = __builtin_amdgcn_cvt_f32_fp8(rh, 0);
      cre[5] = __builtin_amdgcn_cvt_f32_fp8(rh, 1);
      cre[6] = __builtin_amdgcn_cvt_f32_fp8(rh, 2);
      cre[7] = __builtin_amdgcn_cvt_f32_fp8(rh, 3);
      cim[0] = __builtin_amdgcn_cvt_f32_fp8(il, 0);
      cim[1] = __builtin_amdgcn_cvt_f32_fp8(il, 1);
      cim[2] = __builtin_amdgcn_cvt_f32_fp8(il, 2);
      cim[3] = __builtin_amdgcn_cvt_f32_fp8(il, 3);
      cim[4] = __builtin_amdgcn_cvt_f32_fp8(ih, 0);
      cim[5] = __builtin_amdgcn_cvt_f32_fp8(ih, 1);
      cim[6] = __builtin_amdgcn_cvt_f32_fp8(ih, 2);
      cim[7] = __builtin_amdgcn_cvt_f32_fp8(ih, 3);
    }
    float nr[8], ni[8];
    float ss = 0.f;
#pragma unroll
    for (int j = 0; j < 8; ++j) {
      const float a  = zre[j], bb = zim[j];
      const float rr = fmaf(a, a, fmaf(-bb, bb, cre[j]));
      const float ii = fmaf(2.f * a, bb, cim[j]);
      nr[j] = rr; ni[j] = ii;
      ss = fmaf(rr, rr, ss);
      ss = fmaf(ii, ii, ss);
    }
#pragma unroll
    for (int off = 32; off; off >>= 1) ss += __shfl_xor(ss, off);
    const float nrm = sqrtf(ss + 1e-12f);
    const float sc  = 2.0f / fmaxf(nrm, 2.0f);
#pragma unroll
    for (int j = 0; j < 8; ++j) { zre[j] = nr[j] * sc; zim[j] = ni[j] * sc; }
    if (t >= t0) {
      u8* yrow = y + ((size_t)b * S_DIM + t) * D_DIM;
      int pr0 = __builtin_amdgcn_cvt_pk_fp8_f32(16.f * zre[0], 16.f * zre[1], 0, false);
      pr0 = __builtin_amdgcn_cvt_pk_fp8_f32(16.f * zre[2], 16.f * zre[3], pr0, true);
      int pr1 = __builtin_amdgcn_cvt_pk_fp8_f32(16.f * zre[4], 16.f * zre[5], 0, false);
      pr1 = __builtin_amdgcn_cvt_pk_fp8_f32(16.f * zre[6], 16.f * zre[7], pr1, true);
      int pi0 = __builtin_amdgcn_cvt_pk_fp8_f32(16.f * zim[0], 16.f * zim[1], 0, false);
      pi0 = __builtin_amdgcn_cvt_pk_fp8_f32(16.f * zim[2], 16.f * zim[3], pi0, true);
      int pi1 = __builtin_amdgcn_cvt_pk_fp8_f32(16.f * zim[4], 16.f * zim[5], 0, false);
      pi1 = __builtin_amdgcn_cvt_pk_fp8_f32(16.f * zim[6], 16.f * zim[7], pi1, true);
      *(u64*)(yrow + lane * 8)       = ((u64)(unsigned)pr1 << 32) | (unsigned)pr0;
      *(u64*)(yrow + 512 + lane * 8) = ((u64)(unsigned)pi1 << 32) | (unsigned)pi0;
    }
    cr = crn; ci = cin;
  }
}

extern "C" void kernel_launch(void* const* d_in, const int* in_sizes, int n_in,
                              void* d_out, int out_size, void* d_ws, size_t ws_size,
                              hipStream_t stream) {
  const float* x     = (const float*)d_in[0];
  const float* gamma = (const float*)d_in[1];
  const float* beta  = (const float*)d_in[2];
  const float* W_in  = (const float*)d_in[3];
  const float* b_in  = (const float*)d_in[4];
  const float* W_out = (const float*)d_in[5];
  const float* b_out = (const float*)d_in[6];
  float* out = (float*)d_out;

  char* ws = (char*)d_ws;
  u8* hy8  = (u8*)(ws);                  // 16 MiB: h fp8, then y fp8 (alias)
  u8* c8   = (u8*)(ws + (16ull << 20));  // 16 MiB: c fp8
  u8* wti8 = (u8*)(ws + (64ull << 20));  // 1 MiB:  W_in^T  fp8 (x16)
  u8* wto8 = (u8*)(ws + (65ull << 20));  // 1 MiB:  W_out^T fp8 (x16)

  transpose_fp8_kernel<<<dim3(32, 32, 2), 256, 0, stream>>>(W_in, wti8,
                                                            W_out, wto8);
  ln_kernel<<<M_DIM / 4, 256, 0, stream>>>(x, gamma, beta, hy8);
  gemm_mx_kernel<0><<<1024, 256, 0, stream>>>(hy8, wti8, b_in, nullptr, c8);
  scan_kernel<<<dim3(S_DIM / CHUNK, B_DIM), 64, 0, stream>>>(c8, hy8);
  gemm_mx_kernel<1><<<1024, 256, 0, stream>>>(hy8, wto8, b_out, x, out);
}